// Round 6
// baseline (164.500 us; speedup 1.0000x reference)
//
#include <hip/hip_runtime.h>
#include <hip/hip_bf16.h>
#include <stdint.h>

typedef unsigned short u16;
typedef __attribute__((ext_vector_type(8))) short bf16x8;
typedef __attribute__((ext_vector_type(4))) float f32x4;
typedef __attribute__((ext_vector_type(16))) float f32x16;

#define NR 8192     // B*L rows
#define DM 512      // model dim
#define NH 8
#define HD 64
#define LQ 1024

// fold 1/sqrt(64) * log2(e) into LN-q so scores are in exp2 domain
#define QSCALE (0.125f * 1.4426950408889634f)
// fixed softmax offset (safe: |s| <= 512*0.125*log2e = 92 by Cauchy-Schwarz)
#define SOFF 16.0f

__device__ __forceinline__ u16 f2b(float f) {
    union { float f; uint32_t u; } v; v.f = f;
    uint32_t r = v.u + 0x7fffu + ((v.u >> 16) & 1u);   // RNE
    return (u16)(r >> 16);
}
// packed f32x2 -> bf16x2 (v_cvt_pk_bf16_f32, RNE)
__device__ __forceinline__ uint32_t pk2(float lo, float hi) {
    __hip_bfloat162 h = __float22bfloat162_rn(make_float2(lo, hi));
    union { __hip_bfloat162 h; uint32_t u; } c; c.h = h;
    return c.u;
}

// ---------------------------------------------------------------------------
// f32 -> bf16 bulk convert, fused q/k/v (8 elems/thread), grid (2048, 3)
// ---------------------------------------------------------------------------
__global__ __launch_bounds__(256)
void conv3_kernel(const float* __restrict__ q, const float* __restrict__ k,
                  const float* __restrict__ v, u16* __restrict__ qo,
                  u16* __restrict__ ko, u16* __restrict__ vo)
{
    const int y = blockIdx.y;
    const float* in = y == 0 ? q : y == 1 ? k : v;
    u16* out = y == 0 ? qo : y == 1 ? ko : vo;
    const int i = blockIdx.x * 256 + threadIdx.x;
    const float4* p = (const float4*)in + (size_t)i * 2;
    float4 a = p[0], b = p[1];
    uint4 o;
    o.x = pk2(a.x, a.y);
    o.y = pk2(a.z, a.w);
    o.z = pk2(b.x, b.y);
    o.w = pk2(b.z, b.w);
    ((uint4*)out)[i] = o;
}

// ---------------------------------------------------------------------------
// W [K=512][N=512] f32 -> Wt [N][K] bf16, fused x5, grid (8, 8, 5)
// ---------------------------------------------------------------------------
__global__ __launch_bounds__(256)
void wt5_kernel(const float* __restrict__ W0, const float* __restrict__ W1,
                const float* __restrict__ W2, const float* __restrict__ W3,
                const float* __restrict__ W4,
                u16* __restrict__ T0, u16* __restrict__ T1, u16* __restrict__ T2,
                u16* __restrict__ T3, u16* __restrict__ T4)
{
    const int z = blockIdx.z;
    const float* W = z == 0 ? W0 : z == 1 ? W1 : z == 2 ? W2 : z == 3 ? W3 : W4;
    u16* Wt = z == 0 ? T0 : z == 1 ? T1 : z == 2 ? T2 : z == 3 ? T3 : T4;

    __shared__ float S[64][65];
    const int k0 = blockIdx.x * 64, n0 = blockIdx.y * 64;
    #pragma unroll
    for (int p = 0; p < 16; ++p) {
        int idx = threadIdx.x + p * 256;
        int r = idx >> 6, c = idx & 63;
        S[r][c] = W[(size_t)(k0 + r) * DM + n0 + c];
    }
    __syncthreads();
    #pragma unroll
    for (int p = 0; p < 16; ++p) {
        int idx = threadIdx.x + p * 256;
        int r = idx >> 6, c = idx & 63;
        Wt[(size_t)(n0 + r) * DM + k0 + c] = f2b(S[c][r]);
    }
}

// ---------------------------------------------------------------------------
// V [row(b,l)][h*64+d] bf16 -> Vt [b][h][d=64][l=1024] bf16
// ---------------------------------------------------------------------------
__global__ __launch_bounds__(256)
void vt_kernel(const u16* __restrict__ vn, u16* __restrict__ vt)
{
    __shared__ u16 S[64][82];
    const int lt = blockIdx.x, bh = blockIdx.y;
    const int b = bh >> 3, h = bh & 7;
    const int t = threadIdx.x;
    {
        const int r = t >> 2, dc = (t & 3) * 16;
        const u16* src = vn + (size_t)(b * LQ + lt * 64 + r) * DM + h * HD + dc;
        *(uint4*)&S[r][dc]     = *(const uint4*)(src);
        *(uint4*)&S[r][dc + 8] = *(const uint4*)(src + 8);
    }
    __syncthreads();
    {
        const int d = t >> 2, lc = (t & 3) * 16;
        u16 tmp[16];
        #pragma unroll
        for (int e = 0; e < 16; ++e) tmp[e] = S[lc + e][d];
        u16* dst = vt + (((size_t)bh * HD + d) << 10) + lt * 64 + lc;
        *(uint4*)dst       = *(uint4*)&tmp[0];
        *(uint4*)(dst + 8) = *(uint4*)&tmp[8];
    }
}

// ---------------------------------------------------------------------------
// LayerNorm rows of 512, f32 in -> bf16 out, fused q/k/v, grid (NR, 3)
// ---------------------------------------------------------------------------
__global__ __launch_bounds__(256)
void ln3_kernel(const float* __restrict__ Pq, const float* __restrict__ Pk,
                const float* __restrict__ Pv,
                const float* __restrict__ gq, const float* __restrict__ bq,
                const float* __restrict__ gk, const float* __restrict__ bk,
                const float* __restrict__ gv, const float* __restrict__ bv,
                u16* __restrict__ oq, u16* __restrict__ ok, u16* __restrict__ ov)
{
    const int y = blockIdx.y;
    const float* P  = y == 0 ? Pq : y == 1 ? Pk : Pv;
    const float* gm = y == 0 ? gq : y == 1 ? gk : gv;
    const float* be = y == 0 ? bq : y == 1 ? bk : bv;
    u16* out = y == 0 ? oq : y == 1 ? ok : ov;
    const float scale = y == 0 ? QSCALE : 1.f;

    const int row = blockIdx.x, t = threadIdx.x;
    const size_t off = (size_t)row * DM + t * 2;
    float2 v = *(const float2*)(P + off);
    float s = v.x + v.y, s2 = v.x * v.x + v.y * v.y;
    #pragma unroll
    for (int o = 32; o; o >>= 1) { s += __shfl_down(s, o); s2 += __shfl_down(s2, o); }
    __shared__ float ss[4], ss2[4];
    if ((t & 63) == 0) { ss[t >> 6] = s; ss2[t >> 6] = s2; }
    __syncthreads();
    float S = ss[0] + ss[1] + ss[2] + ss[3];
    float S2 = ss2[0] + ss2[1] + ss2[2] + ss2[3];
    float mu = S * (1.f / DM);
    float var = S2 * (1.f / DM) - mu * mu;
    float rs = rsqrtf(var + 1e-6f);
    float g0 = gm[t * 2] * scale, g1 = gm[t * 2 + 1] * scale;
    float b0 = be[t * 2] * scale, b1 = be[t * 2 + 1] * scale;
    float o0 = (v.x - mu) * rs * g0 + b0;
    float o1 = (v.y - mu) * rs * g1 + b1;
    *(uint32_t*)(out + off) = pk2(o0, o1);
}

// ---------------------------------------------------------------------------
// bf16 MFMA GEMM body: C[M,512] = A[M,512]*Bt^T (+bias)(+relu)
// 128x64 tile, 256 threads = 4 waves (2m x 2n), each wave 64x32.
// LDS 16B-unit layouts: A [granule(4)][row(128)], B [granule(4)][row(64)].
// Same verified fragment/epilogue indexing as rounds 2-5 (wm,wn in {0,1}).
// ---------------------------------------------------------------------------
template<bool RELU, bool OUT_BF16>
__device__ __forceinline__
void gemm_body(const u16* __restrict__ A, const u16* __restrict__ Bt,
               const float* __restrict__ bias, void* __restrict__ Cout)
{
    __shared__ u16 Al[4 * 128 * 8];    // 8 KB
    __shared__ u16 Bl[4 * 64 * 8];     // 4 KB
    const int t = threadIdx.x;
    const int w = t >> 6, l = t & 63;
    const int m0 = blockIdx.x * 128, n0 = blockIdx.y * 64;
    const int wm = w >> 1, wn = w & 1;

    // A staging: units t (sg=t>>7, row=t&127) and t+256 (sg+2, same row)
    const u16* Ap = A + (size_t)(m0 + (t & 127)) * DM + (t >> 7) * 8;
    // B staging: unit t (sg=t>>6, row=t&63)
    const u16* Bp = Bt + (size_t)(n0 + (t & 63)) * DM + (t >> 6) * 8;

    uint4 ga1 = *(const uint4*)Ap;
    uint4 ga2 = *(const uint4*)(Ap + 16);
    uint4 gb  = *(const uint4*)Bp;

    f32x4 acc[4][2];
    #pragma unroll
    for (int mi = 0; mi < 4; ++mi)
        #pragma unroll
        for (int ni = 0; ni < 2; ++ni)
            acc[mi][ni] = {0.f, 0.f, 0.f, 0.f};

    for (int kb = 0; kb < DM / 32; ++kb) {
        __syncthreads();
        *(uint4*)&Al[t * 8]          = ga1;
        *(uint4*)&Al[(t + 256) * 8]  = ga2;
        *(uint4*)&Bl[t * 8]          = gb;
        if (kb + 1 < DM / 32) {
            ga1 = *(const uint4*)(Ap + (kb + 1) * 32);
            ga2 = *(const uint4*)(Ap + (kb + 1) * 32 + 16);
            gb  = *(const uint4*)(Bp + (kb + 1) * 32);
        }
        __syncthreads();
        bf16x8 af[4], bfr[2];
        #pragma unroll
        for (int mi = 0; mi < 4; ++mi)
            af[mi] = *(const bf16x8*)&Al[((l >> 4) * 128 + wm * 64 + mi * 16 + (l & 15)) * 8];
        #pragma unroll
        for (int ni = 0; ni < 2; ++ni)
            bfr[ni] = *(const bf16x8*)&Bl[((l >> 4) * 64 + wn * 32 + ni * 16 + (l & 15)) * 8];
        #pragma unroll
        for (int mi = 0; mi < 4; ++mi)
            #pragma unroll
            for (int ni = 0; ni < 2; ++ni)
                acc[mi][ni] = __builtin_amdgcn_mfma_f32_16x16x32_bf16(af[mi], bfr[ni], acc[mi][ni], 0, 0, 0);
    }

    const int cq = l >> 4, cr = l & 15;
    #pragma unroll
    for (int mi = 0; mi < 4; ++mi) {
        const int row = m0 + wm * 64 + mi * 16 + cq * 4;
        #pragma unroll
        for (int ni = 0; ni < 2; ++ni) {
            const int col = n0 + wn * 32 + ni * 16 + cr;
            const float bb = bias[col];
            #pragma unroll
            for (int j = 0; j < 4; ++j) {
                float vv = acc[mi][ni][j] + bb;
                if (RELU) vv = fmaxf(vv, 0.f);
                if (OUT_BF16) ((u16*)Cout)[(size_t)(row + j) * DM + col] = f2b(vv);
                else          ((float*)Cout)[(size_t)(row + j) * DM + col] = vv;
            }
        }
    }
}

template<bool RELU, bool OUT_BF16>
__global__ __launch_bounds__(256, 4)
void mfma_gemm_kernel(const u16* __restrict__ A, const u16* __restrict__ Bt,
                      const float* __restrict__ bias, void* __restrict__ Cout)
{
    gemm_body<RELU, OUT_BF16>(A, Bt, bias, Cout);
}

// fused q/k/v projection GEMM, grid (64, 8, 3)
__global__ __launch_bounds__(256, 4)
void gemm_qkv_kernel(const u16* __restrict__ qbf, const u16* __restrict__ kbf,
                     const u16* __restrict__ vbf,
                     const u16* __restrict__ WqT, const u16* __restrict__ WkT,
                     const u16* __restrict__ WvT,
                     const float* __restrict__ bq, const float* __restrict__ bk,
                     const float* __restrict__ bv,
                     float* __restrict__ res, float* __restrict__ kp,
                     float* __restrict__ vp)
{
    const int z = blockIdx.z;
    const u16* A    = z == 0 ? qbf : z == 1 ? kbf : vbf;
    const u16* Bt   = z == 0 ? WqT : z == 1 ? WkT : WvT;
    const float* bb = z == 0 ? bq  : z == 1 ? bk  : bv;
    void* C         = z == 0 ? (void*)res : z == 1 ? (void*)kp : (void*)vp;
    gemm_body<false, false>(A, Bt, bb, C);
}

// ---------------------------------------------------------------------------
// MFMA flash attention, swapped-operand 32x32x16, fixed-offset softmax.
// Block = 128 q-rows x (b,h); 4 waves x 32 q-rows; KV tile 64; 512 blocks.
// 1D grid with XCD-aware decode: all 8 q-tiles of one (b,h) on one XCD.
// Lane owns q-row (l&31): S^T = mfma(K,Q) C-init = -SOFF; P = exp2 in-lane;
// P^T via per-wave LDS granule layout; O^T = mfma(V^T, P^T). K ping-pong
// in LDS (2 units/thread); V from pre-transposed global Vt[bh][64][1024].
// ---------------------------------------------------------------------------
__global__ __launch_bounds__(256, 4)
void attn_mfma_kernel(const u16* __restrict__ qn, const u16* __restrict__ kn,
                      const u16* __restrict__ vt, u16* __restrict__ ab)
{
    __shared__ u16 Kl[2][8 * 64 * 8];   // 16 KB, K ping-pong
    __shared__ u16 Pl[4][8 * 32 * 8];   // 16 KB, per-wave P^T

    const int t = threadIdx.x;
    const int w = t >> 6, l = t & 63;
    const int hi = l >> 5, ln = l & 31;

    // XCD-aware decode: bid%8 = XCD (round-robin heuristic); all qt of a
    // (b,h) share an XCD so K/V stay in that XCD's L2.
    const int bid = blockIdx.x;
    const int slot = bid >> 3;
    const int bh = (bid & 7) + 8 * (slot & 7);
    const int qt = slot >> 3;
    const int b = bh >> 3, h = bh & 7;

    const size_t bbase = (size_t)b * LQ * DM + h * HD;
    const int q0 = qt * 128 + w * 32;

    // Q B-fragments: qf[c][e] = Q[q0+ln][c*16 + hi*8 + e]
    bf16x8 qf[4];
    {
        const u16* qp = qn + bbase + (size_t)(q0 + ln) * DM + hi * 8;
        #pragma unroll
        for (int c = 0; c < 4; ++c)
            qf[c] = *(const bf16x8*)(qp + c * 16);
    }

    const u16* Vb = vt + (((size_t)bh * HD + ln) << 10);
    // K staging: thread t owns units t (gd=t>>6, kv=t&63) and t+256 (gd+4)
    const u16* Kg = kn + bbase + (size_t)(t & 63) * DM + (t >> 6) * 8;
    u16* Pw = &Pl[w][0];

    f32x16 oa0, oa1;
    #pragma unroll
    for (int r = 0; r < 16; ++r) { oa0[r] = 0.f; oa1[r] = 0.f; }
    float lsum = 0.f;

    *(uint4*)&Kl[0][t * 8]         = *(const uint4*)Kg;        // tile 0
    *(uint4*)&Kl[0][(t + 256) * 8] = *(const uint4*)(Kg + 32);
    uint4 ka1 = *(const uint4*)(Kg + (size_t)64 * DM);          // tile 1
    uint4 ka2 = *(const uint4*)(Kg + (size_t)64 * DM + 32);
    int cur = 0;

    for (int kt = 0; kt < 16; ++kt) {
        __syncthreads();    // Kl[cur] visible; prior reads of Kl[cur^1] done

        // V^T A-fragments (global, L2-resident)
        uint4 vfr[4][2];
        #pragma unroll
        for (int ks = 0; ks < 4; ++ks)
            #pragma unroll
            for (int dh = 0; dh < 2; ++dh)
                vfr[ks][dh] = *(const uint4*)(Vb + (((size_t)dh * 32) << 10)
                                              + kt * 64 + ks * 16 + hi * 8);

        // ---- S^T[kv][q] - SOFF
        f32x16 sa0, sa1;
        #pragma unroll
        for (int r = 0; r < 16; ++r) { sa0[r] = -SOFF; sa1[r] = -SOFF; }
        #pragma unroll
        for (int c = 0; c < 4; ++c) {
            bf16x8 k0 = *(const bf16x8*)&Kl[cur][((c * 2 + hi) * 64 + ln) * 8];
            bf16x8 k1 = *(const bf16x8*)&Kl[cur][((c * 2 + hi) * 64 + 32 + ln) * 8];
            sa0 = __builtin_amdgcn_mfma_f32_32x32x16_bf16(k0, qf[c], sa0, 0, 0, 0);
            sa1 = __builtin_amdgcn_mfma_f32_32x32x16_bf16(k1, qf[c], sa1, 0, 0, 0);
        }

        // stage next K tile into the other buffer; issue kt+2 loads
        if (kt < 15) {
            *(uint4*)&Kl[cur ^ 1][t * 8]         = ka1;
            *(uint4*)&Kl[cur ^ 1][(t + 256) * 8] = ka2;
            if (kt < 14) {
                ka1 = *(const uint4*)(Kg + (size_t)(kt + 2) * 64 * DM);
                ka2 = *(const uint4*)(Kg + (size_t)(kt + 2) * 64 * DM + 32);
            }
        }

        // ---- P = exp2(s - SOFF); per-lane l accumulation
        #pragma unroll
        for (int r = 0; r < 16; ++r) {
            sa0[r] = __builtin_amdgcn_exp2f(sa0[r]);
            sa1[r] = __builtin_amdgcn_exp2f(sa1[r]);
            lsum += sa0[r] + sa1[r];
        }

        // ---- P^T -> per-wave LDS, granule layout [gkv(8)][q(32)][slot(8)]
        #pragma unroll
        for (int g0 = 0; g0 < 4; ++g0) {
            uint2 w0, w1;
            w0.x = pk2(sa0[4 * g0],     sa0[4 * g0 + 1]);
            w0.y = pk2(sa0[4 * g0 + 2], sa0[4 * g0 + 3]);
            w1.x = pk2(sa1[4 * g0],     sa1[4 * g0 + 1]);
            w1.y = pk2(sa1[4 * g0 + 2], sa1[4 * g0 + 3]);
            *(uint2*)&Pw[(g0 * 32 + ln) * 8 + 4 * hi]       = w0;
            *(uint2*)&Pw[((g0 + 4) * 32 + ln) * 8 + 4 * hi] = w1;
        }

        // ---- O^T += V^T * P^T   (wave-local LDS, no barrier needed)
        #pragma unroll
        for (int ks = 0; ks < 4; ++ks) {
            bf16x8 pa = *(const bf16x8*)&Pw[((ks * 2 + hi) * 32 + ln) * 8];
            union { uint4 u; bf16x8 v; } v0, v1;
            v0.u = vfr[ks][0]; v1.u = vfr[ks][1];
            oa0 = __builtin_amdgcn_mfma_f32_32x32x16_bf16(v0.v, pa, oa0, 0, 0, 0);
            oa1 = __builtin_amdgcn_mfma_f32_32x32x16_bf16(v1.v, pa, oa1, 0, 0, 0);
        }
        cur ^= 1;
    }

    // ---- epilogue: oa0[r] = O^T[d=crow(r,hi)][q=ln], oa1: d+32
    lsum += __shfl_xor(lsum, 32, 64);
    const float rinv = 1.f / lsum;
    u16* op = ab + (size_t)(b * LQ + q0 + ln) * DM + h * HD;
    #pragma unroll
    for (int g = 0; g < 4; ++g) {
        uint2 s0, s1;
        s0.x = pk2(oa0[4 * g] * rinv, oa0[4 * g + 1] * rinv);
        s0.y = pk2(oa0[4 * g + 2] * rinv, oa0[4 * g + 3] * rinv);
        s1.x = pk2(oa1[4 * g] * rinv, oa1[4 * g + 1] * rinv);
        s1.y = pk2(oa1[4 * g + 2] * rinv, oa1[4 * g + 3] * rinv);
        *(uint2*)(op + 8 * g + 4 * hi)      = s0;
        *(uint2*)(op + 32 + 8 * g + 4 * hi) = s1;
    }
}

// ---------------------------------------------------------------------------
extern "C" void kernel_launch(void* const* d_in, const int* in_sizes, int n_in,
                              void* d_out, int out_size, void* d_ws, size_t ws_size,
                              hipStream_t stream)
{
    const float* q    = (const float*)d_in[0];
    const float* k    = (const float*)d_in[1];
    const float* v    = (const float*)d_in[2];
    const float* Wq   = (const float*)d_in[3];
    const float* bq   = (const float*)d_in[4];
    const float* Wk   = (const float*)d_in[5];
    const float* bk   = (const float*)d_in[6];
    const float* Wv   = (const float*)d_in[7];
    const float* bv   = (const float*)d_in[8];
    const float* g_q  = (const float*)d_in[9];
    const float* be_q = (const float*)d_in[10];
    const float* g_k  = (const float*)d_in[11];
    const float* be_k = (const float*)d_in[12];
    const float* g_v  = (const float*)d_in[13];
    const float* be_v = (const float*)d_in[14];
    const float* W1   = (const float*)d_in[15];
    const float* b1   = (const float*)d_in[16];
    const float* W2   = (const float*)d_in[17];
    const float* b2   = (const float*)d_in[18];

    float* outp = (float*)d_out;
    float* res  = outp + (size_t)NR * DM;       // residual = raw qp (f32)

    char* wsb = (char*)d_ws;
    const size_t MB = 1024 * 1024;
    float* kp  = (float*)(wsb);                 // 16 MB (f32 kp)
    float* vp  = (float*)(wsb + 16 * MB);       // 16 MB (f32 vp)
    u16* qbf = (u16*)(wsb + 32 * MB);           // 8 MB: bf16(q), later qn
    u16* kbf = (u16*)(wsb + 40 * MB);           // 8 MB: bf16(k), later kn
    u16* vbf = (u16*)(wsb + 48 * MB);           // 8 MB: bf16(v), later vn
    u16* WqT = (u16*)(wsb + 56 * MB);
    u16* WkT = WqT + 512 * 512;
    u16* WvT = WkT + 512 * 512;
    u16* W1T = WvT + 512 * 512;
    u16* W2T = W1T + 512 * 512;
    u16* abb = (u16*)kp;                        // attn out (8MB) reuses kp
    u16* hbb = (u16*)vp;                        // FFN hidden (8MB), first half of vp
    u16* vtb = (u16*)(wsb + 24 * MB);           // V^T (8MB), second half of vp

    conv3_kernel<<<dim3(2048, 3), 256, 0, stream>>>(q, k, v, qbf, kbf, vbf);

    wt5_kernel<<<dim3(8, 8, 5), 256, 0, stream>>>(Wq, Wk, Wv, W1, W2,
                                                  WqT, WkT, WvT, W1T, W2T);

    gemm_qkv_kernel<<<dim3(NR / 128, DM / 64, 3), 256, 0, stream>>>(
        qbf, kbf, vbf, WqT, WkT, WvT, bq, bk, bv, res, kp, vp);

    ln3_kernel<<<dim3(NR, 3), 256, 0, stream>>>(res, kp, vp,
                                                g_q, be_q, g_k, be_k, g_v, be_v,
                                                qbf, kbf, vbf);

    vt_kernel<<<dim3(16, 64), 256, 0, stream>>>(vbf, vtb);

    attn_mfma_kernel<<<512, 256, 0, stream>>>(qbf, kbf, vtb, abb);

    dim3 gg(NR / 128, DM / 64);
    mfma_gemm_kernel<true,  true ><<<gg, 256, 0, stream>>>(abb, W1T, b1, (void*)hbb);
    mfma_gemm_kernel<false, false><<<gg, 256, 0, stream>>>(hbb, W2T, b2, (void*)outp);
}

// Round 7
// 127.715 us; speedup vs baseline: 1.2880x; 1.2880x over previous
//
#include <hip/hip_runtime.h>
#include <hip/hip_bf16.h>
#include <stdint.h>

typedef unsigned short u16;
typedef __attribute__((ext_vector_type(8))) short bf16x8;
typedef __attribute__((ext_vector_type(4))) float f32x4;
typedef __attribute__((ext_vector_type(16))) float f32x16;

#define NR 8192     // B*L rows
#define DM 512      // model dim
#define NH 8
#define HD 64
#define LQ 1024

// fold 1/sqrt(64) * log2(e) into LN-q so scores are in exp2 domain
#define QSCALE (0.125f * 1.4426950408889634f)
// fixed softmax offset (safe: |s| <= 512*0.125*log2e = 92 by Cauchy-Schwarz)
#define SOFF 16.0f

__device__ __forceinline__ u16 f2b(float f) {
    union { float f; uint32_t u; } v; v.f = f;
    uint32_t r = v.u + 0x7fffu + ((v.u >> 16) & 1u);   // RNE
    return (u16)(r >> 16);
}
// packed f32x2 -> bf16x2 (v_cvt_pk_bf16_f32, RNE)
__device__ __forceinline__ uint32_t pk2(float lo, float hi) {
    __hip_bfloat162 h = __float22bfloat162_rn(make_float2(lo, hi));
    union { __hip_bfloat162 h; uint32_t u; } c; c.h = h;
    return c.u;
}

// ---------------------------------------------------------------------------
// f32 -> bf16 bulk convert, fused q/k/v (8 elems/thread), grid (2048, 3)
// ---------------------------------------------------------------------------
__global__ __launch_bounds__(256)
void conv3_kernel(const float* __restrict__ q, const float* __restrict__ k,
                  const float* __restrict__ v, u16* __restrict__ qo,
                  u16* __restrict__ ko, u16* __restrict__ vo)
{
    const int y = blockIdx.y;
    const float* in = y == 0 ? q : y == 1 ? k : v;
    u16* out = y == 0 ? qo : y == 1 ? ko : vo;
    const int i = blockIdx.x * 256 + threadIdx.x;
    const float4* p = (const float4*)in + (size_t)i * 2;
    float4 a = p[0], b = p[1];
    uint4 o;
    o.x = pk2(a.x, a.y);
    o.y = pk2(a.z, a.w);
    o.z = pk2(b.x, b.y);
    o.w = pk2(b.z, b.w);
    ((uint4*)out)[i] = o;
}

// ---------------------------------------------------------------------------
// W [K=512][N=512] f32 -> Wt [N][K] bf16, fused x5, grid (8, 8, 5)
// ---------------------------------------------------------------------------
__global__ __launch_bounds__(256)
void wt5_kernel(const float* __restrict__ W0, const float* __restrict__ W1,
                const float* __restrict__ W2, const float* __restrict__ W3,
                const float* __restrict__ W4,
                u16* __restrict__ T0, u16* __restrict__ T1, u16* __restrict__ T2,
                u16* __restrict__ T3, u16* __restrict__ T4)
{
    const int z = blockIdx.z;
    const float* W = z == 0 ? W0 : z == 1 ? W1 : z == 2 ? W2 : z == 3 ? W3 : W4;
    u16* Wt = z == 0 ? T0 : z == 1 ? T1 : z == 2 ? T2 : z == 3 ? T3 : T4;

    __shared__ float S[64][65];
    const int k0 = blockIdx.x * 64, n0 = blockIdx.y * 64;
    #pragma unroll
    for (int p = 0; p < 16; ++p) {
        int idx = threadIdx.x + p * 256;
        int r = idx >> 6, c = idx & 63;
        S[r][c] = W[(size_t)(k0 + r) * DM + n0 + c];
    }
    __syncthreads();
    #pragma unroll
    for (int p = 0; p < 16; ++p) {
        int idx = threadIdx.x + p * 256;
        int r = idx >> 6, c = idx & 63;
        Wt[(size_t)(n0 + r) * DM + k0 + c] = f2b(S[c][r]);
    }
}

// ---------------------------------------------------------------------------
// V [row(b,l)][h*64+d] bf16 -> Vt [b][h][d=64][l=1024] bf16
// ---------------------------------------------------------------------------
__global__ __launch_bounds__(256)
void vt_kernel(const u16* __restrict__ vn, u16* __restrict__ vt)
{
    __shared__ u16 S[64][82];
    const int lt = blockIdx.x, bh = blockIdx.y;
    const int b = bh >> 3, h = bh & 7;
    const int t = threadIdx.x;
    {
        const int r = t >> 2, dc = (t & 3) * 16;
        const u16* src = vn + (size_t)(b * LQ + lt * 64 + r) * DM + h * HD + dc;
        *(uint4*)&S[r][dc]     = *(const uint4*)(src);
        *(uint4*)&S[r][dc + 8] = *(const uint4*)(src + 8);
    }
    __syncthreads();
    {
        const int d = t >> 2, lc = (t & 3) * 16;
        u16 tmp[16];
        #pragma unroll
        for (int e = 0; e < 16; ++e) tmp[e] = S[lc + e][d];
        u16* dst = vt + (((size_t)bh * HD + d) << 10) + lt * 64 + lc;
        *(uint4*)dst       = *(uint4*)&tmp[0];
        *(uint4*)(dst + 8) = *(uint4*)&tmp[8];
    }
}

// ---------------------------------------------------------------------------
// LayerNorm rows of 512, f32 in -> bf16 out, fused q/k/v, grid (NR, 3)
// ---------------------------------------------------------------------------
__global__ __launch_bounds__(256)
void ln3_kernel(const float* __restrict__ Pq, const float* __restrict__ Pk,
                const float* __restrict__ Pv,
                const float* __restrict__ gq, const float* __restrict__ bq,
                const float* __restrict__ gk, const float* __restrict__ bk,
                const float* __restrict__ gv, const float* __restrict__ bv,
                u16* __restrict__ oq, u16* __restrict__ ok, u16* __restrict__ ov)
{
    const int y = blockIdx.y;
    const float* P  = y == 0 ? Pq : y == 1 ? Pk : Pv;
    const float* gm = y == 0 ? gq : y == 1 ? gk : gv;
    const float* be = y == 0 ? bq : y == 1 ? bk : bv;
    u16* out = y == 0 ? oq : y == 1 ? ok : ov;
    const float scale = y == 0 ? QSCALE : 1.f;

    const int row = blockIdx.x, t = threadIdx.x;
    const size_t off = (size_t)row * DM + t * 2;
    float2 v = *(const float2*)(P + off);
    float s = v.x + v.y, s2 = v.x * v.x + v.y * v.y;
    #pragma unroll
    for (int o = 32; o; o >>= 1) { s += __shfl_down(s, o); s2 += __shfl_down(s2, o); }
    __shared__ float ss[4], ss2[4];
    if ((t & 63) == 0) { ss[t >> 6] = s; ss2[t >> 6] = s2; }
    __syncthreads();
    float S = ss[0] + ss[1] + ss[2] + ss[3];
    float S2 = ss2[0] + ss2[1] + ss2[2] + ss2[3];
    float mu = S * (1.f / DM);
    float var = S2 * (1.f / DM) - mu * mu;
    float rs = rsqrtf(var + 1e-6f);
    float g0 = gm[t * 2] * scale, g1 = gm[t * 2 + 1] * scale;
    float b0 = be[t * 2] * scale, b1 = be[t * 2 + 1] * scale;
    float o0 = (v.x - mu) * rs * g0 + b0;
    float o1 = (v.y - mu) * rs * g1 + b1;
    *(uint32_t*)(out + off) = pk2(o0, o1);
}

// ---------------------------------------------------------------------------
// bf16 MFMA GEMM body (round-5 verified): C[M,512] = A*Bt^T (+bias)(+relu)
// 128x128 tile, 512 threads = 8 waves (2m x 4n), each wave 64x32.
// ---------------------------------------------------------------------------
template<bool RELU, bool OUT_BF16>
__device__ __forceinline__
void gemm_body(const u16* __restrict__ A, const u16* __restrict__ Bt,
               const float* __restrict__ bias, void* __restrict__ Cout)
{
    __shared__ u16 Al[4 * 128 * 8];
    __shared__ u16 Bl[4 * 128 * 8];
    const int t = threadIdx.x;
    const int w = t >> 6, l = t & 63;
    const int m0 = blockIdx.x * 128, n0 = blockIdx.y * 128;
    const int sg = w & 3, sr = (w >> 2) * 64;
    const int wm = w >> 2, wn = w & 3;

    const u16* Ap = A  + (size_t)(m0 + sr + l) * DM + sg * 8;
    const u16* Bp = Bt + (size_t)(n0 + sr + l) * DM + sg * 8;
    const int su = (sg * 128 + sr + l) * 8;

    uint4 ga = *(const uint4*)Ap;
    uint4 gb = *(const uint4*)Bp;

    f32x4 acc[4][2];
    #pragma unroll
    for (int mi = 0; mi < 4; ++mi)
        #pragma unroll
        for (int ni = 0; ni < 2; ++ni)
            acc[mi][ni] = {0.f, 0.f, 0.f, 0.f};

    for (int kb = 0; kb < DM / 32; ++kb) {
        __syncthreads();
        *(uint4*)&Al[su] = ga;
        *(uint4*)&Bl[su] = gb;
        if (kb + 1 < DM / 32) {
            ga = *(const uint4*)(Ap + (kb + 1) * 32);
            gb = *(const uint4*)(Bp + (kb + 1) * 32);
        }
        __syncthreads();
        bf16x8 af[4], bfr[2];
        #pragma unroll
        for (int mi = 0; mi < 4; ++mi)
            af[mi] = *(const bf16x8*)&Al[((l >> 4) * 128 + wm * 64 + mi * 16 + (l & 15)) * 8];
        #pragma unroll
        for (int ni = 0; ni < 2; ++ni)
            bfr[ni] = *(const bf16x8*)&Bl[((l >> 4) * 128 + wn * 32 + ni * 16 + (l & 15)) * 8];
        #pragma unroll
        for (int mi = 0; mi < 4; ++mi)
            #pragma unroll
            for (int ni = 0; ni < 2; ++ni)
                acc[mi][ni] = __builtin_amdgcn_mfma_f32_16x16x32_bf16(af[mi], bfr[ni], acc[mi][ni], 0, 0, 0);
    }

    const int cq = l >> 4, cr = l & 15;
    #pragma unroll
    for (int mi = 0; mi < 4; ++mi) {
        const int row = m0 + wm * 64 + mi * 16 + cq * 4;
        #pragma unroll
        for (int ni = 0; ni < 2; ++ni) {
            const int col = n0 + wn * 32 + ni * 16 + cr;
            const float bb = bias[col];
            #pragma unroll
            for (int j = 0; j < 4; ++j) {
                float vv = acc[mi][ni][j] + bb;
                if (RELU) vv = fmaxf(vv, 0.f);
                if (OUT_BF16) ((u16*)Cout)[(size_t)(row + j) * DM + col] = f2b(vv);
                else          ((float*)Cout)[(size_t)(row + j) * DM + col] = vv;
            }
        }
    }
}

template<bool RELU, bool OUT_BF16>
__global__ __launch_bounds__(512)
void mfma_gemm_kernel(const u16* __restrict__ A, const u16* __restrict__ Bt,
                      const float* __restrict__ bias, void* __restrict__ Cout)
{
    gemm_body<RELU, OUT_BF16>(A, Bt, bias, Cout);
}

// fused q/k/v projection GEMM, grid (64, 4, 3)
__global__ __launch_bounds__(512)
void gemm_qkv_kernel(const u16* __restrict__ qbf, const u16* __restrict__ kbf,
                     const u16* __restrict__ vbf,
                     const u16* __restrict__ WqT, const u16* __restrict__ WkT,
                     const u16* __restrict__ WvT,
                     const float* __restrict__ bq, const float* __restrict__ bk,
                     const float* __restrict__ bv,
                     float* __restrict__ res, float* __restrict__ kp,
                     float* __restrict__ vp)
{
    const int z = blockIdx.z;
    const u16* A    = z == 0 ? qbf : z == 1 ? kbf : vbf;
    const u16* Bt   = z == 0 ? WqT : z == 1 ? WkT : WvT;
    const float* bb = z == 0 ? bq  : z == 1 ? bk  : bv;
    void* C         = z == 0 ? (void*)res : z == 1 ? (void*)kp : (void*)vp;
    gemm_body<false, false>(A, Bt, bb, C);
}

// ---------------------------------------------------------------------------
// MFMA flash attention, swapped-operand 32x32x16, fixed-offset softmax.
// Block = 128 q-rows x (b,h); 4 waves x 32 q-rows; KV tile 64; 512 blocks.
// K AND V ping-pong staged in LDS (coalesced global loads); V fragments
// from LDS units [gkv(8)][d(64)] (conflict-optimal reads, same as K).
// Lane owns q-row (l&31): S^T = mfma(K,Q) C-init = -SOFF; P = exp2 in-lane;
// P^T via per-wave LDS granule layout; O^T = mfma(V^T, P^T).
// ---------------------------------------------------------------------------
__global__ __launch_bounds__(256, 3)
void attn_mfma_kernel(const u16* __restrict__ qn, const u16* __restrict__ kn,
                      const u16* __restrict__ vt, u16* __restrict__ ab)
{
    __shared__ u16 Kl[2][8 * 64 * 8];   // 16 KB, K ping-pong, [gd(8)][kv(64)]
    __shared__ u16 Vl[2][8 * 64 * 8];   // 16 KB, V ping-pong, [gkv(8)][d(64)]
    __shared__ u16 Pl[4][8 * 32 * 8];   // 16 KB, per-wave P^T

    const int t = threadIdx.x;
    const int w = t >> 6, l = t & 63;
    const int hi = l >> 5, ln = l & 31;

    // XCD-aware decode: all 8 q-tiles of a (b,h) share an XCD for K/V L2 reuse.
    const int bid = blockIdx.x;
    const int slot = bid >> 3;
    const int bh = (bid & 7) + 8 * (slot & 7);
    const int qt = slot >> 3;
    const int b = bh >> 3, h = bh & 7;

    const size_t bbase = (size_t)b * LQ * DM + h * HD;
    const int q0 = qt * 128 + w * 32;

    // Q B-fragments: qf[c][e] = Q[q0+ln][c*16 + hi*8 + e]
    bf16x8 qf[4];
    {
        const u16* qp = qn + bbase + (size_t)(q0 + ln) * DM + hi * 8;
        #pragma unroll
        for (int c = 0; c < 4; ++c)
            qf[c] = *(const bf16x8*)(qp + c * 16);
    }

    // K staging: thread t owns units t (gd=t>>6, kv=t&63) and t+256 (gd+4)
    const u16* Kg = kn + bbase + (size_t)(t & 63) * DM + (t >> 6) * 8;
    // V staging from Vt[bh][d][l]: thread t owns (d=t>>3, gkv=t&7) and (d+32, gkv)
    // global: 8 consecutive lanes read 128B contiguous of one d-row (coalesced)
    const u16* Vg = vt + (((size_t)bh * HD + (t >> 3)) << 10) + (t & 7) * 8;
    const int svu1 = ((t & 7) * 64 + (t >> 3)) * 8;        // LDS unit (gkv, d)
    const int svu2 = ((t & 7) * 64 + 32 + (t >> 3)) * 8;   // LDS unit (gkv, d+32)
    u16* Pw = &Pl[w][0];

    f32x16 oa0, oa1;
    #pragma unroll
    for (int r = 0; r < 16; ++r) { oa0[r] = 0.f; oa1[r] = 0.f; }
    float lsum = 0.f;

    // stage tile 0, prefetch tile 1
    *(uint4*)&Kl[0][t * 8]         = *(const uint4*)Kg;
    *(uint4*)&Kl[0][(t + 256) * 8] = *(const uint4*)(Kg + 32);
    *(uint4*)&Vl[0][svu1]          = *(const uint4*)Vg;
    *(uint4*)&Vl[0][svu2]          = *(const uint4*)(Vg + (32 << 10));
    uint4 ka1 = *(const uint4*)(Kg + (size_t)64 * DM);
    uint4 ka2 = *(const uint4*)(Kg + (size_t)64 * DM + 32);
    uint4 va1 = *(const uint4*)(Vg + 64);
    uint4 va2 = *(const uint4*)(Vg + (32 << 10) + 64);
    int cur = 0;

    for (int kt = 0; kt < 16; ++kt) {
        __syncthreads();    // [cur] staged; prior reads of [cur^1] done

        // ---- S^T[kv][q] - SOFF
        f32x16 sa0, sa1;
        #pragma unroll
        for (int r = 0; r < 16; ++r) { sa0[r] = -SOFF; sa1[r] = -SOFF; }
        #pragma unroll
        for (int c = 0; c < 4; ++c) {
            bf16x8 k0 = *(const bf16x8*)&Kl[cur][((c * 2 + hi) * 64 + ln) * 8];
            bf16x8 k1 = *(const bf16x8*)&Kl[cur][((c * 2 + hi) * 64 + 32 + ln) * 8];
            sa0 = __builtin_amdgcn_mfma_f32_32x32x16_bf16(k0, qf[c], sa0, 0, 0, 0);
            sa1 = __builtin_amdgcn_mfma_f32_32x32x16_bf16(k1, qf[c], sa1, 0, 0, 0);
        }

        // stage next tile into other buffer; issue kt+2 loads
        if (kt < 15) {
            *(uint4*)&Kl[cur ^ 1][t * 8]         = ka1;
            *(uint4*)&Kl[cur ^ 1][(t + 256) * 8] = ka2;
            *(uint4*)&Vl[cur ^ 1][svu1]          = va1;
            *(uint4*)&Vl[cur ^ 1][svu2]          = va2;
            if (kt < 14) {
                ka1 = *(const uint4*)(Kg + (size_t)(kt + 2) * 64 * DM);
                ka2 = *(const uint4*)(Kg + (size_t)(kt + 2) * 64 * DM + 32);
                va1 = *(const uint4*)(Vg + (kt + 2) * 64);
                va2 = *(const uint4*)(Vg + (32 << 10) + (kt + 2) * 64);
            }
        }

        // ---- P = exp2(s - SOFF); per-lane l accumulation
        #pragma unroll
        for (int r = 0; r < 16; ++r) {
            sa0[r] = __builtin_amdgcn_exp2f(sa0[r]);
            sa1[r] = __builtin_amdgcn_exp2f(sa1[r]);
            lsum += sa0[r] + sa1[r];
        }

        // ---- P^T -> per-wave LDS, granule layout [gkv(8)][q(32)][slot(8)]
        #pragma unroll
        for (int g0 = 0; g0 < 4; ++g0) {
            uint2 w0, w1;
            w0.x = pk2(sa0[4 * g0],     sa0[4 * g0 + 1]);
            w0.y = pk2(sa0[4 * g0 + 2], sa0[4 * g0 + 3]);
            w1.x = pk2(sa1[4 * g0],     sa1[4 * g0 + 1]);
            w1.y = pk2(sa1[4 * g0 + 2], sa1[4 * g0 + 3]);
            *(uint2*)&Pw[(g0 * 32 + ln) * 8 + 4 * hi]       = w0;
            *(uint2*)&Pw[((g0 + 4) * 32 + ln) * 8 + 4 * hi] = w1;
        }

        // ---- O^T += V^T * P^T   (wave-local P, block-shared V from LDS)
        #pragma unroll
        for (int ks = 0; ks < 4; ++ks) {
            bf16x8 pa = *(const bf16x8*)&Pw[((ks * 2 + hi) * 32 + ln) * 8];
            bf16x8 v0 = *(const bf16x8*)&Vl[cur][((ks * 2 + hi) * 64 + ln) * 8];
            bf16x8 v1 = *(const bf16x8*)&Vl[cur][((ks * 2 + hi) * 64 + 32 + ln) * 8];
            oa0 = __builtin_amdgcn_mfma_f32_32x32x16_bf16(v0, pa, oa0, 0, 0, 0);
            oa1 = __builtin_amdgcn_mfma_f32_32x32x16_bf16(v1, pa, oa1, 0, 0, 0);
        }
        cur ^= 1;
    }

    // ---- epilogue: oa0[r] = O^T[d=crow(r,hi)][q=ln], oa1: d+32
    lsum += __shfl_xor(lsum, 32, 64);
    const float rinv = 1.f / lsum;
    u16* op = ab + (size_t)(b * LQ + q0 + ln) * DM + h * HD;
    #pragma unroll
    for (int g = 0; g < 4; ++g) {
        uint2 s0, s1;
        s0.x = pk2(oa0[4 * g] * rinv, oa0[4 * g + 1] * rinv);
        s0.y = pk2(oa0[4 * g + 2] * rinv, oa0[4 * g + 3] * rinv);
        s1.x = pk2(oa1[4 * g] * rinv, oa1[4 * g + 1] * rinv);
        s1.y = pk2(oa1[4 * g + 2] * rinv, oa1[4 * g + 3] * rinv);
        *(uint2*)(op + 8 * g + 4 * hi)      = s0;
        *(uint2*)(op + 32 + 8 * g + 4 * hi) = s1;
    }
}

// ---------------------------------------------------------------------------
extern "C" void kernel_launch(void* const* d_in, const int* in_sizes, int n_in,
                              void* d_out, int out_size, void* d_ws, size_t ws_size,
                              hipStream_t stream)
{
    const float* q    = (const float*)d_in[0];
    const float* k    = (const float*)d_in[1];
    const float* v    = (const float*)d_in[2];
    const float* Wq   = (const float*)d_in[3];
    const float* bq   = (const float*)d_in[4];
    const float* Wk   = (const float*)d_in[5];
    const float* bk   = (const float*)d_in[6];
    const float* Wv   = (const float*)d_in[7];
    const float* bv   = (const float*)d_in[8];
    const float* g_q  = (const float*)d_in[9];
    const float* be_q = (const float*)d_in[10];
    const float* g_k  = (const float*)d_in[11];
    const float* be_k = (const float*)d_in[12];
    const float* g_v  = (const float*)d_in[13];
    const float* be_v = (const float*)d_in[14];
    const float* W1   = (const float*)d_in[15];
    const float* b1   = (const float*)d_in[16];
    const float* W2   = (const float*)d_in[17];
    const float* b2   = (const float*)d_in[18];

    float* outp = (float*)d_out;
    float* res  = outp + (size_t)NR * DM;       // residual = raw qp (f32)

    char* wsb = (char*)d_ws;
    const size_t MB = 1024 * 1024;
    float* kp  = (float*)(wsb);                 // 16 MB (f32 kp)
    float* vp  = (float*)(wsb + 16 * MB);       // 16 MB (f32 vp)
    u16* qbf = (u16*)(wsb + 32 * MB);           // 8 MB: bf16(q), later qn
    u16* kbf = (u16*)(wsb + 40 * MB);           // 8 MB: bf16(k), later kn
    u16* vbf = (u16*)(wsb + 48 * MB);           // 8 MB: bf16(v), later vn
    u16* WqT = (u16*)(wsb + 56 * MB);
    u16* WkT = WqT + 512 * 512;
    u16* WvT = WkT + 512 * 512;
    u16* W1T = WvT + 512 * 512;
    u16* W2T = W1T + 512 * 512;
    u16* abb = (u16*)kp;                        // attn out (8MB) reuses kp
    u16* hbb = (u16*)vp;                        // FFN hidden (8MB), first half of vp
    u16* vtb = (u16*)(wsb + 24 * MB);           // V^T (8MB), second half of vp

    conv3_kernel<<<dim3(2048, 3), 256, 0, stream>>>(q, k, v, qbf, kbf, vbf);

    wt5_kernel<<<dim3(8, 8, 5), 256, 0, stream>>>(Wq, Wk, Wv, W1, W2,
                                                  WqT, WkT, WvT, W1T, W2T);

    gemm_qkv_kernel<<<dim3(NR / 128, DM / 128, 3), 512, 0, stream>>>(
        qbf, kbf, vbf, WqT, WkT, WvT, bq, bk, bv, res, kp, vp);

    ln3_kernel<<<dim3(NR, 3), 256, 0, stream>>>(res, kp, vp,
                                                g_q, be_q, g_k, be_k, g_v, be_v,
                                                qbf, kbf, vbf);

    vt_kernel<<<dim3(16, 64), 256, 0, stream>>>(vbf, vtb);

    attn_mfma_kernel<<<512, 256, 0, stream>>>(qbf, kbf, vtb, abb);

    dim3 gg(NR / 128, DM / 128);
    mfma_gemm_kernel<true,  true ><<<gg, 512, 0, stream>>>(abb, W1T, b1, (void*)hbb);
    mfma_gemm_kernel<false, false><<<gg, 512, 0, stream>>>(hbb, W2T, b2, (void*)outp);
}